// Round 8
// baseline (179.190 us; speedup 1.0000x reference)
//
#include <hip/hip_runtime.h>
#include <hip/hip_bf16.h>

// Causal MHA: B=2 N=2048 D=1024 H=16 DH=64. fp32 in/out, bf16 MFMA internal.
// R16 = R15 with the flash main loop software-pipelined intra-wave:
//   QK(0); for t in 0..7: { QK(t+1) || exp/pack(t) || PV(t-1) }; PV(7)
// plus s_setprio(1/0) around MFMA clusters (T5, m191 +4-7% on attn) and
// staging LDS-writes issued before PV(7) so they drain under it.
// Rationale: R15 proved barrier count is NOT the cost (per-64-key cycles
// invariant 2887 vs 2890); regime is latency-bound at 2 waves/SIMD with
// MFMA 22% / VALU 26% / LDS 34% — the serial QK->exp2->pack->PV chain
// leaves all pipes idle. This round overlaps the chain classes within a
// wave: QK(t+1) covers sA(t)->exp2 latency; PV (matrix pipe) overlaps
// exp2 (trans pipe). Same math, same traffic, pure reorder.
// KVBLK=128, 4 waves x 2 strips, LDS 70.7 KB, 2 blocks/CU. GEMMs + fused
// cast unchanged.

typedef __hip_bfloat16 bf16;
typedef short bf16x8 __attribute__((ext_vector_type(8)));   // 4 VGPR (K=32 MFMA A/B)
typedef short bf16x4 __attribute__((ext_vector_type(4)));   // 2 VGPR (K=16 MFMA A/B)
typedef float f32x4 __attribute__((ext_vector_type(4)));    // MFMA C/D frag

#define QSCALE 0.1803368801111204f   // 0.125 * log2(e): S in log2 domain

typedef __attribute__((address_space(3))) unsigned int lds_u32;
typedef const __attribute__((address_space(1))) unsigned int glob_u32;

__device__ __forceinline__ void glds16(const void* g, void* l) {
    __builtin_amdgcn_global_load_lds((glob_u32*)g, (lds_u32*)l, 16, 0, 0);
}

__device__ __forceinline__ short f2bf(float f) {
    __hip_bfloat16 h = __float2bfloat16(f);
    return *reinterpret_cast<short*>(&h);
}

// pack two f32 -> two bf16 (round-to-nearest-up) in one u32: {hi16(b), hi16(a)}
__device__ __forceinline__ unsigned pack_bf16(float a, float b) {
    unsigned au = __builtin_bit_cast(unsigned, a) + 0x8000u;
    unsigned bu = __builtin_bit_cast(unsigned, b) + 0x8000u;
    return __builtin_amdgcn_perm(bu, au, 0x07060302u);  // bytes: b[3],b[2],a[3],a[2]
}

// ---------------- fused cast fp32 -> bf16 for x, W_qkv, W_out ----------------
__global__ void cast_all(const float* __restrict__ x, const float* __restrict__ wqkv,
                         const float* __restrict__ wout,
                         bf16* __restrict__ xb, bf16* __restrict__ wqkvb,
                         bf16* __restrict__ woutb) {
    int i = blockIdx.x * blockDim.x + threadIdx.x;   // 0 .. 2097151 (x4 elems)
    const float4* s; short4* d; int o;
    if (i < 1048576)               { s = (const float4*)x;    d = (short4*)xb;    o = i; }
    else if (i < 1835008)          { s = (const float4*)wqkv; d = (short4*)wqkvb; o = i - 1048576; }
    else                           { s = (const float4*)wout; d = (short4*)woutb; o = i - 1835008; }
    float4 f = s[o];
    short4 v;
    v.x = f2bf(f.x); v.y = f2bf(f.y); v.z = f2bf(f.z); v.w = f2bf(f.w);
    d[o] = v;
}

// ---------- GEMM 128x128: C[M,Nc] = A[M,K] @ Bt[Nc,K]^T (both K-major) -------
// global_load_lds width=16, XOR-swizzled LDS slots, double-buffered.
// EPI=0: scatter to q/k/v [b,h,n,dh] (q pre-scaled). EPI=1: fp32 C.
template<int EPI>
__global__ __launch_bounds__(256)
void gemm128(const bf16* __restrict__ A, const bf16* __restrict__ Bt,
             float* __restrict__ Cf,
             bf16* __restrict__ qp, bf16* __restrict__ kp, bf16* __restrict__ vp,
             int K, int Ncols) {
    __shared__ alignas(16) short As[2][4096];   // 8 KB/buf
    __shared__ alignas(16) short Bs[2][4096];

    const int tid = threadIdx.x;
    const int wave = tid >> 6, lane = tid & 63;
    const int quad = lane >> 4, l16 = lane & 15;
    const int wm = wave >> 1, wn = wave & 1;
    const int m0 = blockIdx.x * 128;
    const int n0 = blockIdx.y * 128;

    f32x4 acc[4][4] = {};

    const int srow = tid >> 2;
    const int skk  = (((tid & 3) ^ ((tid >> 3) & 3))) * 8;
    const bf16* Ag = A  + (size_t)(m0 + srow) * K + skk;
    const bf16* Bg = Bt + (size_t)(n0 + srow) * K + skk;
    const size_t rowskip = (size_t)64 * K;
    short* Asl = &As[0][0] + tid * 8;
    short* Bsl = &Bs[0][0] + tid * 8;

    const int xk = (quad ^ ((l16 >> 1) & 3)) * 8;
    const int arow = wm * 64 + l16;
    const int brow = wn * 64 + l16;

    const int KI = K >> 5;
    glds16(Ag, Asl);
    glds16(Ag + rowskip, Asl + 2048);
    glds16(Bg, Bsl);
    glds16(Bg + rowskip, Bsl + 2048);
    __syncthreads();

    int buf = 0;
    for (int ki = 0; ki < KI; ++ki) {
        if (ki + 1 < KI) {
            const bf16* ag = Ag + (ki + 1) * 32;
            const bf16* bg = Bg + (ki + 1) * 32;
            short* ad = Asl + (buf ^ 1) * 4096;
            short* bd = Bsl + (buf ^ 1) * 4096;
            glds16(ag, ad);
            glds16(ag + rowskip, ad + 2048);
            glds16(bg, bd);
            glds16(bg + rowskip, bd + 2048);
        }
        const short* ab = &As[buf][0];
        const short* bb = &Bs[buf][0];
        bf16x8 af[4], bf[4];
        #pragma unroll
        for (int mt = 0; mt < 4; ++mt)
            af[mt] = *reinterpret_cast<const bf16x8*>(ab + (arow + mt * 16) * 32 + xk);
        #pragma unroll
        for (int nt = 0; nt < 4; ++nt)
            bf[nt] = *reinterpret_cast<const bf16x8*>(bb + (brow + nt * 16) * 32 + xk);
        #pragma unroll
        for (int mt = 0; mt < 4; ++mt)
            #pragma unroll
            for (int nt = 0; nt < 4; ++nt)
                acc[mt][nt] = __builtin_amdgcn_mfma_f32_16x16x32_bf16(
                    af[mt], bf[nt], acc[mt][nt], 0, 0, 0);
        __syncthreads();
        buf ^= 1;
    }

    #pragma unroll
    for (int mt = 0; mt < 4; ++mt) {
        #pragma unroll
        for (int nt = 0; nt < 4; ++nt) {
            #pragma unroll
            for (int r = 0; r < 4; ++r) {
                int gm = m0 + wm * 64 + mt * 16 + quad * 4 + r;
                int gn = n0 + wn * 64 + nt * 16 + l16;
                float val = acc[mt][nt][r];
                if (EPI == 0) {
                    int sel = gn >> 10, rem = gn & 1023;
                    int h = rem >> 6, dh = rem & 63;
                    int b = gm >> 11, nq = gm & 2047;
                    if (sel == 0) val *= QSCALE;
                    bf16* dst = (sel == 0) ? qp : ((sel == 1) ? kp : vp);
                    dst[((((size_t)b * 16 + h) * 2048) + nq) * 64 + dh] = __float2bfloat16(val);
                } else {
                    Cf[(size_t)gm * Ncols + gn] = val;
                }
            }
        }
    }
}

// ---------------- flash attention (causal), S^T form, 128-row q-tiles --------
// grid (32 bh, 16 y->qt), block 256 = 4 waves. Wave w owns TWO q-strips:
// A = rows Q0+16w..+15, B = rows Q0+64+16w..+15. K/V LDS frags shared by both
// strips. KVBLK=128 keys per step (t=0..7), double-buffered, software-
// pipelined: QK(t+1) || exp/pack(t) || PV(t-1), setprio around MFMA clusters.
__global__ __launch_bounds__(256, 2)
void flash_attn(const bf16* __restrict__ Q, const bf16* __restrict__ K,
                const bf16* __restrict__ V, bf16* __restrict__ O) {
    __shared__ alignas(16) short Ks[2][128][72];   // [buf][key][dh], +8 pad  (36.9 KB)
    __shared__ alignas(16) short Vt[2][64][132];   // [buf][dh][key], +4 pad  (33.8 KB)

    const int tid = threadIdx.x;
    const int wave = tid >> 6, lane = tid & 63;
    const int quad = lane >> 4, l16 = lane & 15;
    const int bh = blockIdx.x;
    const int yy = blockIdx.y;
    const int qt = (yy < 8) ? yy : (15 - (yy & 7));   // pair y,y+8 -> 17 steps/CU
    const int Q0 = qt * 128;
    const float NEG_INF = -__builtin_inff();

    const bf16* Qb = Q + (size_t)bh * 2048 * 64;
    const bf16* Kb = K + (size_t)bh * 2048 * 64;
    const bf16* Vb = V + (size_t)bh * 2048 * 64;

    // Q B-frags for both strips
    const int qrowA = Q0 + wave * 16 + l16;
    const int qrowB = qrowA + 64;
    const bf16x8 qfA0 = *reinterpret_cast<const bf16x8*>(Qb + (size_t)qrowA * 64 + quad * 8);
    const bf16x8 qfA1 = *reinterpret_cast<const bf16x8*>(Qb + (size_t)qrowA * 64 + 32 + quad * 8);
    const bf16x8 qfB0 = *reinterpret_cast<const bf16x8*>(Qb + (size_t)qrowB * 64 + quad * 8);
    const bf16x8 qfB1 = *reinterpret_cast<const bf16x8*>(Qb + (size_t)qrowB * 64 + 32 + quad * 8);

    float lA = 0.f, lB = 0.f;
    f32x4 oA[4] = {}, oB[4] = {};

    const int krow = tid >> 2;           // K: row 0..63 (plus +64 group)
    const int kcol = (tid & 3) * 16;     // K: col chunk
    const int kb   = (tid & 15) * 4;     // V: key rows kb..kb+3 (plus +64 group)
    const int db   = (tid >> 4) * 4;     // V: dh cols db..db+3

    {   // prologue: stage 128-key tile j0=0 into buf 0
        #pragma unroll
        for (int g = 0; g < 2; ++g) {
            const bf16* kr = Kb + (size_t)(g * 64 + krow) * 64 + kcol;
            *reinterpret_cast<bf16x8*>(&Ks[0][g * 64 + krow][kcol])     = *reinterpret_cast<const bf16x8*>(kr);
            *reinterpret_cast<bf16x8*>(&Ks[0][g * 64 + krow][kcol + 8]) = *reinterpret_cast<const bf16x8*>(kr + 8);
        }
        #pragma unroll
        for (int g = 0; g < 2; ++g) {
            const int kbg = g * 64 + kb;
            bf16x4 L0 = *reinterpret_cast<const bf16x4*>(Vb + (size_t)(kbg + 0) * 64 + db);
            bf16x4 L1 = *reinterpret_cast<const bf16x4*>(Vb + (size_t)(kbg + 1) * 64 + db);
            bf16x4 L2 = *reinterpret_cast<const bf16x4*>(Vb + (size_t)(kbg + 2) * 64 + db);
            bf16x4 L3 = *reinterpret_cast<const bf16x4*>(Vb + (size_t)(kbg + 3) * 64 + db);
            #pragma unroll
            for (int j = 0; j < 4; ++j) {
                bf16x4 w; w[0] = L0[j]; w[1] = L1[j]; w[2] = L2[j]; w[3] = L3[j];
                *reinterpret_cast<bf16x4*>(&Vt[0][db + j][kbg]) = w;
            }
        }
    }
    __syncthreads();

    int buf = 0;
    // ---- main loop: j0 < Q0, full 128-key tiles, prefetch j0+128 ----
    for (int j0 = 0; j0 < Q0; j0 += 128) {
        const bf16* Kn = Kb + (size_t)(j0 + 128) * 64;
        const bf16* Vn = Vb + (size_t)(j0 + 128) * 64;
        bf16x8 nk[2][2];
        bf16x4 NV[2][4];
        #pragma unroll
        for (int g = 0; g < 2; ++g) {
            const bf16* kr = Kn + (size_t)(g * 64 + krow) * 64 + kcol;
            nk[g][0] = *reinterpret_cast<const bf16x8*>(kr);
            nk[g][1] = *reinterpret_cast<const bf16x8*>(kr + 8);
            const int kbg = g * 64 + kb;
            #pragma unroll
            for (int j = 0; j < 4; ++j)
                NV[g][j] = *reinterpret_cast<const bf16x4*>(Vn + (size_t)(kbg + j) * 64 + db);
        }

        bf16x4 pkA[8], pkB[8];
        f32x4 sA, sB, sAn, sBn;
        {   // QK(0)
            bf16x8 k0 = *reinterpret_cast<const bf16x8*>(&Ks[buf][l16][quad * 8]);
            bf16x8 k1 = *reinterpret_cast<const bf16x8*>(&Ks[buf][l16][32 + quad * 8]);
            __builtin_amdgcn_s_setprio(1);
            sA = {}; sB = {};
            sA = __builtin_amdgcn_mfma_f32_16x16x32_bf16(k0, qfA0, sA, 0, 0, 0);
            sA = __builtin_amdgcn_mfma_f32_16x16x32_bf16(k1, qfA1, sA, 0, 0, 0);
            sB = __builtin_amdgcn_mfma_f32_16x16x32_bf16(k0, qfB0, sB, 0, 0, 0);
            sB = __builtin_amdgcn_mfma_f32_16x16x32_bf16(k1, qfB1, sB, 0, 0, 0);
            __builtin_amdgcn_s_setprio(0);
        }
        #pragma unroll
        for (int t = 0; t < 8; ++t) {
            if (t < 7) {   // QK(t+1): covers sA(t)/sB(t) -> exp2 latency
                bf16x8 k0 = *reinterpret_cast<const bf16x8*>(&Ks[buf][16 * (t + 1) + l16][quad * 8]);
                bf16x8 k1 = *reinterpret_cast<const bf16x8*>(&Ks[buf][16 * (t + 1) + l16][32 + quad * 8]);
                __builtin_amdgcn_s_setprio(1);
                sAn = {}; sBn = {};
                sAn = __builtin_amdgcn_mfma_f32_16x16x32_bf16(k0, qfA0, sAn, 0, 0, 0);
                sAn = __builtin_amdgcn_mfma_f32_16x16x32_bf16(k1, qfA1, sAn, 0, 0, 0);
                sBn = __builtin_amdgcn_mfma_f32_16x16x32_bf16(k0, qfB0, sBn, 0, 0, 0);
                sBn = __builtin_amdgcn_mfma_f32_16x16x32_bf16(k1, qfB1, sBn, 0, 0, 0);
                __builtin_amdgcn_s_setprio(0);
            }
            // exp/pack(t) on the trans/VALU pipes
            float a0 = __builtin_amdgcn_exp2f(sA[0]);
            float a1 = __builtin_amdgcn_exp2f(sA[1]);
            float a2 = __builtin_amdgcn_exp2f(sA[2]);
            float a3 = __builtin_amdgcn_exp2f(sA[3]);
            float b0 = __builtin_amdgcn_exp2f(sB[0]);
            float b1 = __builtin_amdgcn_exp2f(sB[1]);
            float b2 = __builtin_amdgcn_exp2f(sB[2]);
            float b3 = __builtin_amdgcn_exp2f(sB[3]);
            lA += (a0 + a1) + (a2 + a3);
            lB += (b0 + b1) + (b2 + b3);
            unsigned* pa = reinterpret_cast<unsigned*>(&pkA[t]);
            pa[0] = pack_bf16(a0, a1); pa[1] = pack_bf16(a2, a3);
            unsigned* pb = reinterpret_cast<unsigned*>(&pkB[t]);
            pb[0] = pack_bf16(b0, b1); pb[1] = pack_bf16(b2, b3);
            if (t > 0) {   // PV(t-1): matrix pipe, overlaps exp2(t) trans pipe
                __builtin_amdgcn_s_setprio(1);
                #pragma unroll
                for (int dt = 0; dt < 4; ++dt) {
                    bf16x4 vf = *reinterpret_cast<const bf16x4*>(
                        &Vt[buf][dt * 16 + l16][(t - 1) * 16 + quad * 4]);
                    oA[dt] = __builtin_amdgcn_mfma_f32_16x16x16bf16_1k(vf, pkA[t - 1], oA[dt], 0, 0, 0);
                    oB[dt] = __builtin_amdgcn_mfma_f32_16x16x16bf16_1k(vf, pkB[t - 1], oB[dt], 0, 0, 0);
                }
                __builtin_amdgcn_s_setprio(0);
            }
            if (t < 7) { sA = sAn; sB = sBn; }
        }

        // staging writes to buf^1 (issue before PV(7); drain under it + barrier)
        #pragma unroll
        for (int g = 0; g < 2; ++g) {
            *reinterpret_cast<bf16x8*>(&Ks[buf ^ 1][g * 64 + krow][kcol])     = nk[g][0];
            *reinterpret_cast<bf16x8*>(&Ks[buf ^ 1][g * 64 + krow][kcol + 8]) = nk[g][1];
            const int kbg = g * 64 + kb;
            #pragma unroll
            for (int j = 0; j < 4; ++j) {
                bf16x4 w; w[0] = NV[g][0][j]; w[1] = NV[g][1][j]; w[2] = NV[g][2][j]; w[3] = NV[g][3][j];
                *reinterpret_cast<bf16x4*>(&Vt[buf ^ 1][db + j][kbg]) = w;
            }
        }

        {   // PV(7)
            __builtin_amdgcn_s_setprio(1);
            #pragma unroll
            for (int dt = 0; dt < 4; ++dt) {
                bf16x4 vf = *reinterpret_cast<const bf16x4*>(
                    &Vt[buf][dt * 16 + l16][7 * 16 + quad * 4]);
                oA[dt] = __builtin_amdgcn_mfma_f32_16x16x16bf16_1k(vf, pkA[7], oA[dt], 0, 0, 0);
                oB[dt] = __builtin_amdgcn_mfma_f32_16x16x16bf16_1k(vf, pkB[7], oB[dt], 0, 0, 0);
            }
            __builtin_amdgcn_s_setprio(0);
        }
        __syncthreads();
        buf ^= 1;
    }

    // ---- tail: diagonal 128-key tile at j0 = Q0 (runs once; simple form) ----
    // strip A: full t<wave, diag t==wave; strip B: full t<wave+4, diag t==wave+4
    {
        bf16x4 pkA[8], pkB[8];
        #pragma unroll
        for (int t = 0; t < 8; ++t) {
            const bool actB = (t <= wave + 4);
            const bool actA = (t <= wave);
            if (actB) {
                bf16x8 k0 = *reinterpret_cast<const bf16x8*>(&Ks[buf][16 * t + l16][quad * 8]);
                bf16x8 k1 = *reinterpret_cast<const bf16x8*>(&Ks[buf][16 * t + l16][32 + quad * 8]);
                f32x4 sB = {};
                sB = __builtin_amdgcn_mfma_f32_16x16x32_bf16(k0, qfB0, sB, 0, 0, 0);
                sB = __builtin_amdgcn_mfma_f32_16x16x32_bf16(k1, qfB1, sB, 0, 0, 0);
                if (t == wave + 4) {
                    #pragma unroll
                    for (int r = 0; r < 4; ++r)
                        if (quad * 4 + r > l16) sB[r] = NEG_INF;   // key > qrowB
                }
                float b0 = __builtin_amdgcn_exp2f(sB[0]);   // exp2(-inf)=0
                float b1 = __builtin_amdgcn_exp2f(sB[1]);
                float b2 = __builtin_amdgcn_exp2f(sB[2]);
                float b3 = __builtin_amdgcn_exp2f(sB[3]);
                lB += (b0 + b1) + (b2 + b3);
                unsigned* pb = reinterpret_cast<unsigned*>(&pkB[t]);
                pb[0] = pack_bf16(b0, b1); pb[1] = pack_bf16(b2, b3);
                if (actA) {
                    f32x4 sA = {};
                    sA = __builtin_amdgcn_mfma_f32_16x16x32_bf16(k0, qfA0, sA, 0, 0, 0);
                    sA = __builtin_amdgcn_mfma_f32_16x16x32_bf16(k1, qfA1, sA, 0, 0, 0);
                    if (t == wave) {
                        #pragma unroll
                        for (int r = 0; r < 4; ++r)
                            if (quad * 4 + r > l16) sA[r] = NEG_INF;   // key > qrowA
                    }
                    float a0 = __builtin_amdgcn_exp2f(sA[0]);
                    float a1 = __builtin_amdgcn_exp2f(sA[1]);
                    float a2 = __builtin_amdgcn_exp2f(sA[2]);
                    float a3 = __builtin_amdgcn_exp2f(sA[3]);
                    lA += (a0 + a1) + (a2 + a3);
                    unsigned* pa = reinterpret_cast<unsigned*>(&pkA[t]);
                    pa[0] = pack_bf16(a0, a1); pa[1] = pack_bf16(a2, a3);
                }
            }
        }
        #pragma unroll
        for (int t = 0; t < 8; ++t) {
            if (t <= wave + 4) {
                #pragma unroll
                for (int dt = 0; dt < 4; ++dt) {
                    bf16x4 vf = *reinterpret_cast<const bf16x4*>(
                        &Vt[buf][dt * 16 + l16][t * 16 + quad * 4]);
                    oB[dt] = __builtin_amdgcn_mfma_f32_16x16x16bf16_1k(vf, pkB[t], oB[dt], 0, 0, 0);
                    if (t <= wave)
                        oA[dt] = __builtin_amdgcn_mfma_f32_16x16x16bf16_1k(vf, pkA[t], oA[dt], 0, 0, 0);
                }
            }
        }
    }

    // ---- reduce l across quads, normalize, store both strips ----
    lA += __shfl_xor(lA, 16, 64);
    lA += __shfl_xor(lA, 32, 64);
    lB += __shfl_xor(lB, 16, 64);
    lB += __shfl_xor(lB, 32, 64);
    const float invA = 1.f / lA;
    const float invB = 1.f / lB;

    const int b = bh >> 4, h = bh & 15;
    bf16* orowA = O + ((size_t)b * 2048 + qrowA) * 1024 + h * 64;
    bf16* orowB = O + ((size_t)b * 2048 + qrowB) * 1024 + h * 64;
    #pragma unroll
    for (int dt = 0; dt < 4; ++dt) {
        bf16x4 wA, wB;
        unsigned* ua = reinterpret_cast<unsigned*>(&wA);
        ua[0] = pack_bf16(oA[dt][0] * invA, oA[dt][1] * invA);
        ua[1] = pack_bf16(oA[dt][2] * invA, oA[dt][3] * invA);
        *reinterpret_cast<bf16x4*>(orowA + dt * 16 + quad * 4) = wA;
        unsigned* ub = reinterpret_cast<unsigned*>(&wB);
        ub[0] = pack_bf16(oB[dt][0] * invB, oB[dt][1] * invB);
        ub[1] = pack_bf16(oB[dt][2] * invB, oB[dt][3] * invB);
        *reinterpret_cast<bf16x4*>(orowB + dt * 16 + quad * 4) = wB;
    }
}

extern "C" void kernel_launch(void* const* d_in, const int* in_sizes, int n_in,
                              void* d_out, int out_size, void* d_ws, size_t ws_size,
                              hipStream_t stream) {
    const float* x    = (const float*)d_in[0];
    // d_in[1] = mask (int32 tril) — causal is hardcoded
    const float* Wqkv = (const float*)d_in[2];
    const float* Wout = (const float*)d_in[3];
    float* out = (float*)d_out;

    char* ws = (char*)d_ws;
    bf16* x_bf    = (bf16*)(ws);                  //  8 MB  [4096,1024]
    bf16* wqkv_bf = (bf16*)(ws + 8388608);        //  6 MB  [3072,1024]
    bf16* wout_bf = (bf16*)(ws + 14680064);       //  2 MB  [1024,1024]
    bf16* q       = (bf16*)(ws + 16777216);       //  8 MB  [32,2048,64] (pre-scaled)
    bf16* k       = (bf16*)(ws + 25165824);       //  8 MB
    bf16* v       = (bf16*)(ws + 33554432);       //  8 MB
    bf16* ao      = (bf16*)(ws + 41943040);       //  8 MB  [4096,1024]

    cast_all<<<8192, 256, 0, stream>>>(x, Wqkv, Wout, x_bf, wqkv_bf, wout_bf);
    gemm128<0><<<dim3(32, 24), 256, 0, stream>>>(x_bf, wqkv_bf, nullptr, q, k, v, 1024, 3072);
    flash_attn<<<dim3(32, 16), 256, 0, stream>>>(q, k, v, ao);
    gemm128<1><<<dim3(32, 8), 256, 0, stream>>>(ao, wout_bf, out, nullptr, nullptr, nullptr, 1024, 1024);
}

// Round 9
// 175.999 us; speedup vs baseline: 1.0181x; 1.0181x over previous
//
#include <hip/hip_runtime.h>
#include <hip/hip_bf16.h>

// Causal MHA: B=2 N=2048 D=1024 H=16 DH=64. fp32 in/out, bf16 MFMA internal.
// R17 = R16 with two independent changes:
// (1) flash: all 16 K-frag ds_reads of a 128-key step hoisted into regs
//     (kf[8][2], ~64 VGPR) at step start — removes the 8x per-step
//     ds_read->MFMA latency exposure (prime suspect: LDS 53% / MFMA 21% /
//     VALU 26%, nothing saturated => latency-bound; R12 proved the 85 B/cyc
//     LDS ceiling, R15 sits at 53% of it).
// (2) out-projection retiled 128x128 -> 128x64 (gemm_out, grid 32x16 = 512
//     blocks = 2/CU instead of 1/CU): m114 inter-block overlap hides the
//     per-K-step barrier drain. B staging halves; LDS 24 KB.
// Casts + QKV gemm unchanged.

typedef __hip_bfloat16 bf16;
typedef short bf16x8 __attribute__((ext_vector_type(8)));   // 4 VGPR (K=32 MFMA A/B)
typedef short bf16x4 __attribute__((ext_vector_type(4)));   // 2 VGPR (K=16 MFMA A/B)
typedef float f32x4 __attribute__((ext_vector_type(4)));    // MFMA C/D frag

#define QSCALE 0.1803368801111204f   // 0.125 * log2(e): S in log2 domain

typedef __attribute__((address_space(3))) unsigned int lds_u32;
typedef const __attribute__((address_space(1))) unsigned int glob_u32;

__device__ __forceinline__ void glds16(const void* g, void* l) {
    __builtin_amdgcn_global_load_lds((glob_u32*)g, (lds_u32*)l, 16, 0, 0);
}

__device__ __forceinline__ short f2bf(float f) {
    __hip_bfloat16 h = __float2bfloat16(f);
    return *reinterpret_cast<short*>(&h);
}

// pack two f32 -> two bf16 (round-to-nearest-up) in one u32: {hi16(b), hi16(a)}
__device__ __forceinline__ unsigned pack_bf16(float a, float b) {
    unsigned au = __builtin_bit_cast(unsigned, a) + 0x8000u;
    unsigned bu = __builtin_bit_cast(unsigned, b) + 0x8000u;
    return __builtin_amdgcn_perm(bu, au, 0x07060302u);  // bytes: b[3],b[2],a[3],a[2]
}

// ---------------- fused cast fp32 -> bf16 for x, W_qkv, W_out ----------------
__global__ void cast_all(const float* __restrict__ x, const float* __restrict__ wqkv,
                         const float* __restrict__ wout,
                         bf16* __restrict__ xb, bf16* __restrict__ wqkvb,
                         bf16* __restrict__ woutb) {
    int i = blockIdx.x * blockDim.x + threadIdx.x;   // 0 .. 2097151 (x4 elems)
    const float4* s; short4* d; int o;
    if (i < 1048576)               { s = (const float4*)x;    d = (short4*)xb;    o = i; }
    else if (i < 1835008)          { s = (const float4*)wqkv; d = (short4*)wqkvb; o = i - 1048576; }
    else                           { s = (const float4*)wout; d = (short4*)woutb; o = i - 1835008; }
    float4 f = s[o];
    short4 v;
    v.x = f2bf(f.x); v.y = f2bf(f.y); v.z = f2bf(f.z); v.w = f2bf(f.w);
    d[o] = v;
}

// ---------- GEMM 128x128: C = A @ Bt^T, scatter epilogue to q/k/v ----------
__global__ __launch_bounds__(256)
void gemm128_qkv(const bf16* __restrict__ A, const bf16* __restrict__ Bt,
                 bf16* __restrict__ qp, bf16* __restrict__ kp, bf16* __restrict__ vp,
                 int K) {
    __shared__ alignas(16) short As[2][4096];   // 8 KB/buf
    __shared__ alignas(16) short Bs[2][4096];

    const int tid = threadIdx.x;
    const int wave = tid >> 6, lane = tid & 63;
    const int quad = lane >> 4, l16 = lane & 15;
    const int wm = wave >> 1, wn = wave & 1;
    const int m0 = blockIdx.x * 128;
    const int n0 = blockIdx.y * 128;

    f32x4 acc[4][4] = {};

    const int srow = tid >> 2;
    const int skk  = (((tid & 3) ^ ((tid >> 3) & 3))) * 8;
    const bf16* Ag = A  + (size_t)(m0 + srow) * K + skk;
    const bf16* Bg = Bt + (size_t)(n0 + srow) * K + skk;
    const size_t rowskip = (size_t)64 * K;
    short* Asl = &As[0][0] + tid * 8;
    short* Bsl = &Bs[0][0] + tid * 8;

    const int xk = (quad ^ ((l16 >> 1) & 3)) * 8;
    const int arow = wm * 64 + l16;
    const int brow = wn * 64 + l16;

    const int KI = K >> 5;
    glds16(Ag, Asl);
    glds16(Ag + rowskip, Asl + 2048);
    glds16(Bg, Bsl);
    glds16(Bg + rowskip, Bsl + 2048);
    __syncthreads();

    int buf = 0;
    for (int ki = 0; ki < KI; ++ki) {
        if (ki + 1 < KI) {
            const bf16* ag = Ag + (ki + 1) * 32;
            const bf16* bg = Bg + (ki + 1) * 32;
            short* ad = Asl + (buf ^ 1) * 4096;
            short* bd = Bsl + (buf ^ 1) * 4096;
            glds16(ag, ad);
            glds16(ag + rowskip, ad + 2048);
            glds16(bg, bd);
            glds16(bg + rowskip, bd + 2048);
        }
        const short* ab = &As[buf][0];
        const short* bb = &Bs[buf][0];
        bf16x8 af[4], bf[4];
        #pragma unroll
        for (int mt = 0; mt < 4; ++mt)
            af[mt] = *reinterpret_cast<const bf16x8*>(ab + (arow + mt * 16) * 32 + xk);
        #pragma unroll
        for (int nt = 0; nt < 4; ++nt)
            bf[nt] = *reinterpret_cast<const bf16x8*>(bb + (brow + nt * 16) * 32 + xk);
        #pragma unroll
        for (int mt = 0; mt < 4; ++mt)
            #pragma unroll
            for (int nt = 0; nt < 4; ++nt)
                acc[mt][nt] = __builtin_amdgcn_mfma_f32_16x16x32_bf16(
                    af[mt], bf[nt], acc[mt][nt], 0, 0, 0);
        __syncthreads();
        buf ^= 1;
    }

    #pragma unroll
    for (int mt = 0; mt < 4; ++mt) {
        #pragma unroll
        for (int nt = 0; nt < 4; ++nt) {
            #pragma unroll
            for (int r = 0; r < 4; ++r) {
                int gm = m0 + wm * 64 + mt * 16 + quad * 4 + r;
                int gn = n0 + wn * 64 + nt * 16 + l16;
                float val = acc[mt][nt][r];
                int sel = gn >> 10, rem = gn & 1023;
                int h = rem >> 6, dh = rem & 63;
                int b = gm >> 11, nq = gm & 2047;
                if (sel == 0) val *= QSCALE;
                bf16* dst = (sel == 0) ? qp : ((sel == 1) ? kp : vp);
                dst[((((size_t)b * 16 + h) * 2048) + nq) * 64 + dh] = __float2bfloat16(val);
            }
        }
    }
}

// ---------- GEMM 128x64 (out-projection): C[M,1024] = A @ Bt^T, fp32 C ------
// 512 blocks -> 2/CU: inter-block overlap hides per-K-step barrier drain.
__global__ __launch_bounds__(256)
void gemm_out(const bf16* __restrict__ A, const bf16* __restrict__ Bt,
              float* __restrict__ Cf, int K, int Ncols) {
    __shared__ alignas(16) short As[2][4096];   // 128 rows x 32 k
    __shared__ alignas(16) short Bs[2][2048];   //  64 rows x 32 k

    const int tid = threadIdx.x;
    const int wave = tid >> 6, lane = tid & 63;
    const int quad = lane >> 4, l16 = lane & 15;
    const int wm = wave >> 1, wn = wave & 1;
    const int m0 = blockIdx.x * 128;
    const int n0 = blockIdx.y * 64;

    f32x4 acc[4][2] = {};

    const int srow = tid >> 2;
    const int skk  = (((tid & 3) ^ ((tid >> 3) & 3))) * 8;
    const bf16* Ag = A  + (size_t)(m0 + srow) * K + skk;
    const bf16* Bg = Bt + (size_t)(n0 + srow) * K + skk;   // srow 0..63 covers all B rows
    const size_t rowskip = (size_t)64 * K;
    short* Asl = &As[0][0] + tid * 8;
    short* Bsl = &Bs[0][0] + tid * 8;

    const int xk = (quad ^ ((l16 >> 1) & 3)) * 8;
    const int arow = wm * 64 + l16;
    const int brow = wn * 32 + l16;     // bits 1-2 of wn*32 clear -> swizzle algebra holds

    const int KI = K >> 5;
    glds16(Ag, Asl);
    glds16(Ag + rowskip, Asl + 2048);
    glds16(Bg, Bsl);
    __syncthreads();

    int buf = 0;
    for (int ki = 0; ki < KI; ++ki) {
        if (ki + 1 < KI) {
            const bf16* ag = Ag + (ki + 1) * 32;
            const bf16* bg = Bg + (ki + 1) * 32;
            short* ad = Asl + (buf ^ 1) * 4096;
            short* bd = Bsl + (buf ^ 1) * 2048;
            glds16(ag, ad);
            glds16(ag + rowskip, ad + 2048);
            glds16(bg, bd);
        }
        const short* ab = &As[buf][0];
        const short* bb = &Bs[buf][0];
        bf16x8 af[4], bf[2];
        #pragma unroll
        for (int mt = 0; mt < 4; ++mt)
            af[mt] = *reinterpret_cast<const bf16x8*>(ab + (arow + mt * 16) * 32 + xk);
        #pragma unroll
        for (int nt = 0; nt < 2; ++nt)
            bf[nt] = *reinterpret_cast<const bf16x8*>(bb + (brow + nt * 16) * 32 + xk);
        #pragma unroll
        for (int mt = 0; mt < 4; ++mt)
            #pragma unroll
            for (int nt = 0; nt < 2; ++nt)
                acc[mt][nt] = __builtin_amdgcn_mfma_f32_16x16x32_bf16(
                    af[mt], bf[nt], acc[mt][nt], 0, 0, 0);
        __syncthreads();
        buf ^= 1;
    }

    #pragma unroll
    for (int mt = 0; mt < 4; ++mt) {
        #pragma unroll
        for (int nt = 0; nt < 2; ++nt) {
            #pragma unroll
            for (int r = 0; r < 4; ++r) {
                int gm = m0 + wm * 64 + mt * 16 + quad * 4 + r;
                int gn = n0 + wn * 32 + nt * 16 + l16;
                Cf[(size_t)gm * Ncols + gn] = acc[mt][nt][r];
            }
        }
    }
}

// ---------------- flash attention (causal), S^T form, 128-row q-tiles --------
// grid (32 bh, 16 y->qt), block 256 = 4 waves. Wave w owns TWO q-strips.
// KVBLK=128 per step, double-buffered. Main loop: all 16 K-frag ds_reads
// hoisted to regs at step start (kf[8][2]); QK(t+1) || exp/pack(t) || PV(t-1)
// pipeline; setprio around MFMA clusters; staging writes before PV(7).
__global__ __launch_bounds__(256, 2)
void flash_attn(const bf16* __restrict__ Q, const bf16* __restrict__ K,
                const bf16* __restrict__ V, bf16* __restrict__ O) {
    __shared__ alignas(16) short Ks[2][128][72];   // [buf][key][dh], +8 pad  (36.9 KB)
    __shared__ alignas(16) short Vt[2][64][132];   // [buf][dh][key], +4 pad  (33.8 KB)

    const int tid = threadIdx.x;
    const int wave = tid >> 6, lane = tid & 63;
    const int quad = lane >> 4, l16 = lane & 15;
    const int bh = blockIdx.x;
    const int yy = blockIdx.y;
    const int qt = (yy < 8) ? yy : (15 - (yy & 7));   // pair y,y+8 -> 17 steps/CU
    const int Q0 = qt * 128;
    const float NEG_INF = -__builtin_inff();

    const bf16* Qb = Q + (size_t)bh * 2048 * 64;
    const bf16* Kb = K + (size_t)bh * 2048 * 64;
    const bf16* Vb = V + (size_t)bh * 2048 * 64;

    // Q B-frags for both strips
    const int qrowA = Q0 + wave * 16 + l16;
    const int qrowB = qrowA + 64;
    const bf16x8 qfA0 = *reinterpret_cast<const bf16x8*>(Qb + (size_t)qrowA * 64 + quad * 8);
    const bf16x8 qfA1 = *reinterpret_cast<const bf16x8*>(Qb + (size_t)qrowA * 64 + 32 + quad * 8);
    const bf16x8 qfB0 = *reinterpret_cast<const bf16x8*>(Qb + (size_t)qrowB * 64 + quad * 8);
    const bf16x8 qfB1 = *reinterpret_cast<const bf16x8*>(Qb + (size_t)qrowB * 64 + 32 + quad * 8);

    float lA = 0.f, lB = 0.f;
    f32x4 oA[4] = {}, oB[4] = {};

    const int krow = tid >> 2;           // K: row 0..63 (plus +64 group)
    const int kcol = (tid & 3) * 16;     // K: col chunk
    const int kb   = (tid & 15) * 4;     // V: key rows kb..kb+3 (plus +64 group)
    const int db   = (tid >> 4) * 4;     // V: dh cols db..db+3

    {   // prologue: stage 128-key tile j0=0 into buf 0
        #pragma unroll
        for (int g = 0; g < 2; ++g) {
            const bf16* kr = Kb + (size_t)(g * 64 + krow) * 64 + kcol;
            *reinterpret_cast<bf16x8*>(&Ks[0][g * 64 + krow][kcol])     = *reinterpret_cast<const bf16x8*>(kr);
            *reinterpret_cast<bf16x8*>(&Ks[0][g * 64 + krow][kcol + 8]) = *reinterpret_cast<const bf16x8*>(kr + 8);
        }
        #pragma unroll
        for (int g = 0; g < 2; ++g) {
            const int kbg = g * 64 + kb;
            bf16x4 L0 = *reinterpret_cast<const bf16x4*>(Vb + (size_t)(kbg + 0) * 64 + db);
            bf16x4 L1 = *reinterpret_cast<const bf16x4*>(Vb + (size_t)(kbg + 1) * 64 + db);
            bf16x4 L2 = *reinterpret_cast<const bf16x4*>(Vb + (size_t)(kbg + 2) * 64 + db);
            bf16x4 L3 = *reinterpret_cast<const bf16x4*>(Vb + (size_t)(kbg + 3) * 64 + db);
            #pragma unroll
            for (int j = 0; j < 4; ++j) {
                bf16x4 w; w[0] = L0[j]; w[1] = L1[j]; w[2] = L2[j]; w[3] = L3[j];
                *reinterpret_cast<bf16x4*>(&Vt[0][db + j][kbg]) = w;
            }
        }
    }
    __syncthreads();

    int buf = 0;
    // ---- main loop: j0 < Q0, full 128-key tiles, prefetch j0+128 ----
    for (int j0 = 0; j0 < Q0; j0 += 128) {
        const bf16* Kn = Kb + (size_t)(j0 + 128) * 64;
        const bf16* Vn = Vb + (size_t)(j0 + 128) * 64;
        bf16x8 nk[2][2];
        bf16x4 NV[2][4];
        #pragma unroll
        for (int g = 0; g < 2; ++g) {
            const bf16* kr = Kn + (size_t)(g * 64 + krow) * 64 + kcol;
            nk[g][0] = *reinterpret_cast<const bf16x8*>(kr);
            nk[g][1] = *reinterpret_cast<const bf16x8*>(kr + 8);
            const int kbg = g * 64 + kb;
            #pragma unroll
            for (int j = 0; j < 4; ++j)
                NV[g][j] = *reinterpret_cast<const bf16x4*>(Vn + (size_t)(kbg + j) * 64 + db);
        }

        // ---- hoist: ALL K-frags of this tile into registers, back-to-back ----
        bf16x8 kf[8][2];
        #pragma unroll
        for (int t = 0; t < 8; ++t) {
            kf[t][0] = *reinterpret_cast<const bf16x8*>(&Ks[buf][16 * t + l16][quad * 8]);
            kf[t][1] = *reinterpret_cast<const bf16x8*>(&Ks[buf][16 * t + l16][32 + quad * 8]);
        }

        bf16x4 pkA[8], pkB[8];
        f32x4 sA, sB, sAn, sBn;
        {   // QK(0) — from regs
            __builtin_amdgcn_s_setprio(1);
            sA = {}; sB = {};
            sA = __builtin_amdgcn_mfma_f32_16x16x32_bf16(kf[0][0], qfA0, sA, 0, 0, 0);
            sA = __builtin_amdgcn_mfma_f32_16x16x32_bf16(kf[0][1], qfA1, sA, 0, 0, 0);
            sB = __builtin_amdgcn_mfma_f32_16x16x32_bf16(kf[0][0], qfB0, sB, 0, 0, 0);
            sB = __builtin_amdgcn_mfma_f32_16x16x32_bf16(kf[0][1], qfB1, sB, 0, 0, 0);
            __builtin_amdgcn_s_setprio(0);
        }
        #pragma unroll
        for (int t = 0; t < 8; ++t) {
            if (t < 7) {   // QK(t+1): regs only — no LDS dependency
                __builtin_amdgcn_s_setprio(1);
                sAn = {}; sBn = {};
                sAn = __builtin_amdgcn_mfma_f32_16x16x32_bf16(kf[t + 1][0], qfA0, sAn, 0, 0, 0);
                sAn = __builtin_amdgcn_mfma_f32_16x16x32_bf16(kf[t + 1][1], qfA1, sAn, 0, 0, 0);
                sBn = __builtin_amdgcn_mfma_f32_16x16x32_bf16(kf[t + 1][0], qfB0, sBn, 0, 0, 0);
                sBn = __builtin_amdgcn_mfma_f32_16x16x32_bf16(kf[t + 1][1], qfB1, sBn, 0, 0, 0);
                __builtin_amdgcn_s_setprio(0);
            }
            // exp/pack(t) on the trans/VALU pipes
            float a0 = __builtin_amdgcn_exp2f(sA[0]);
            float a1 = __builtin_amdgcn_exp2f(sA[1]);
            float a2 = __builtin_amdgcn_exp2f(sA[2]);
            float a3 = __builtin_amdgcn_exp2f(sA[3]);
            float b0 = __builtin_amdgcn_exp2f(sB[0]);
            float b1 = __builtin_amdgcn_exp2f(sB[1]);
            float b2 = __builtin_amdgcn_exp2f(sB[2]);
            float b3 = __builtin_amdgcn_exp2f(sB[3]);
            lA += (a0 + a1) + (a2 + a3);
            lB += (b0 + b1) + (b2 + b3);
            unsigned* pa = reinterpret_cast<unsigned*>(&pkA[t]);
            pa[0] = pack_bf16(a0, a1); pa[1] = pack_bf16(a2, a3);
            unsigned* pb = reinterpret_cast<unsigned*>(&pkB[t]);
            pb[0] = pack_bf16(b0, b1); pb[1] = pack_bf16(b2, b3);
            if (t > 0) {   // PV(t-1): matrix pipe, overlaps exp2(t) trans pipe
                __builtin_amdgcn_s_setprio(1);
                #pragma unroll
                for (int dt = 0; dt < 4; ++dt) {
                    bf16x4 vf = *reinterpret_cast<const bf16x4*>(
                        &Vt[buf][dt * 16 + l16][(t - 1) * 16 + quad * 4]);
                    oA[dt] = __builtin_amdgcn_mfma_f32_16x16x16bf16_1k(vf, pkA[t - 1], oA[dt], 0, 0, 0);
                    oB[dt] = __builtin_amdgcn_mfma_f32_16x16x16bf16_1k(vf, pkB[t - 1], oB[dt], 0, 0, 0);
                }
                __builtin_amdgcn_s_setprio(0);
            }
            if (t < 7) { sA = sAn; sB = sBn; }
        }

        // staging writes to buf^1 (issue before PV(7); drain under it + barrier)
        #pragma unroll
        for (int g = 0; g < 2; ++g) {
            *reinterpret_cast<bf16x8*>(&Ks[buf ^ 1][g * 64 + krow][kcol])     = nk[g][0];
            *reinterpret_cast<bf16x8*>(&Ks[buf ^ 1][g * 64 + krow][kcol + 8]) = nk[g][1];
            const int kbg = g * 64 + kb;
            #pragma unroll
            for (int j = 0; j < 4; ++j) {
                bf16x4 w; w[0] = NV[g][0][j]; w[1] = NV[g][1][j]; w[2] = NV[g][2][j]; w[3] = NV[g][3][j];
                *reinterpret_cast<bf16x4*>(&Vt[buf ^ 1][db + j][kbg]) = w;
            }
        }

        {   // PV(7)
            __builtin_amdgcn_s_setprio(1);
            #pragma unroll
            for (int dt = 0; dt < 4; ++dt) {
                bf16x4 vf = *reinterpret_cast<const bf16x4*>(
                    &Vt[buf][dt * 16 + l16][7 * 16 + quad * 4]);
                oA[dt] = __builtin_amdgcn_mfma_f32_16x16x16bf16_1k(vf, pkA[7], oA[dt], 0, 0, 0);
                oB[dt] = __builtin_amdgcn_mfma_f32_16x16x16bf16_1k(vf, pkB[7], oB[dt], 0, 0, 0);
            }
            __builtin_amdgcn_s_setprio(0);
        }
        __syncthreads();
        buf ^= 1;
    }

    // ---- tail: diagonal 128-key tile at j0 = Q0 (runs once; simple form) ----
    {
        bf16x4 pkA[8], pkB[8];
        #pragma unroll
        for (int t = 0; t < 8; ++t) {
            const bool actB = (t <= wave + 4);
            const bool actA = (t <= wave);
            if (actB) {
                bf16x8 k0 = *reinterpret_cast<const bf16x8*>(&Ks[buf][16 * t + l16][quad * 8]);
                bf16x8 k1 = *reinterpret_cast<const bf16x8*>(&Ks[buf][16 * t + l16][32 + quad * 8]);
                f32x4 sB = {};
                sB = __builtin_amdgcn_mfma_f32_16x16x32_bf16(k0, qfB0, sB, 0, 0, 0);
                sB = __builtin_amdgcn_mfma_f32_16x16x32_bf16(k1, qfB1, sB, 0, 0, 0);
                if (t == wave + 4) {
                    #pragma unroll
                    for (int r = 0; r < 4; ++r)
                        if (quad * 4 + r > l16) sB[r] = NEG_INF;   // key > qrowB
                }
                float b0 = __builtin_amdgcn_exp2f(sB[0]);   // exp2(-inf)=0
                float b1 = __builtin_amdgcn_exp2f(sB[1]);
                float b2 = __builtin_amdgcn_exp2f(sB[2]);
                float b3 = __builtin_amdgcn_exp2f(sB[3]);
                lB += (b0 + b1) + (b2 + b3);
                unsigned* pb = reinterpret_cast<unsigned*>(&pkB[t]);
                pb[0] = pack_bf16(b0, b1); pb[1] = pack_bf16(b2, b3);
                if (actA) {
                    f32x4 sA = {};
                    sA = __builtin_amdgcn_mfma_f32_16x16x32_bf16(k0, qfA0, sA, 0, 0, 0);
                    sA = __builtin_amdgcn_mfma_f32_16x16x32_bf16(k1, qfA1, sA, 0, 0, 0);
                    if (t == wave) {
                        #pragma unroll
                        for (int r = 0; r < 4; ++r)
                            if (quad * 4 + r > l16) sA[r] = NEG_INF;   // key > qrowA
                    }
                    float a0 = __builtin_amdgcn_exp2f(sA[0]);
                    float a1 = __builtin_amdgcn_exp2f(sA[1]);
                    float a2 = __builtin_amdgcn_exp2f(sA[2]);
                    float a3 = __builtin_amdgcn_exp2f(sA[3]);
                    lA += (a0 + a1) + (a2 + a3);
                    unsigned* pa = reinterpret_cast<unsigned*>(&pkA[t]);
                    pa[0] = pack_bf16(a0, a1); pa[1] = pack_bf16(a2, a3);
                }
            }
        }
        #pragma unroll
        for (int t = 0; t < 8; ++t) {
            if (t <= wave + 4) {
                #pragma unroll
                for (int dt = 0; dt < 4; ++dt) {
                    bf16x4 vf = *reinterpret_cast<const bf16x4*>(
                        &Vt[buf][dt * 16 + l16][t * 16 + quad * 4]);
                    oB[dt] = __builtin_amdgcn_mfma_f32_16x16x16bf16_1k(vf, pkB[t], oB[dt], 0, 0, 0);
                    if (t <= wave)
                        oA[dt] = __builtin_amdgcn_mfma_f32_16x16x16bf16_1k(vf, pkA[t], oA[dt], 0, 0, 0);
                }
            }
        }
    }

    // ---- reduce l across quads, normalize, store both strips ----
    lA += __shfl_xor(lA, 16, 64);
    lA += __shfl_xor(lA, 32, 64);
    lB += __shfl_xor(lB, 16, 64);
    lB += __shfl_xor(lB, 32, 64);
    const float invA = 1.f / lA;
    const float invB = 1.f / lB;

    const int b = bh >> 4, h = bh & 15;
    bf16* orowA = O + ((size_t)b * 2048 + qrowA) * 1024 + h * 64;
    bf16* orowB = O + ((size_t)b * 2048 + qrowB) * 1024 + h * 64;
    #pragma unroll
    for (int dt = 0; dt < 4; ++dt) {
        bf16x4 wA, wB;
        unsigned* ua = reinterpret_cast<unsigned*>(&wA);
        ua[0] = pack_bf16(oA[dt][0] * invA, oA[dt][1] * invA);
        ua[1] = pack_bf16(oA[dt][2] * invA, oA[dt][3] * invA);
        *reinterpret_cast<bf16x4*>(orowA + dt * 16 + quad * 4) = wA;
        unsigned* ub = reinterpret_cast<unsigned*>(&wB);
        ub[0] = pack_bf16(oB[dt][0] * invB, oB[dt][1] * invB);
        ub[1] = pack_bf16(oB[dt][2] * invB, oB[dt][3] * invB);
        *reinterpret_cast<bf16x4*>(orowB + dt * 16 + quad * 4) = wB;
    }
}

extern "C" void kernel_launch(void* const* d_in, const int* in_sizes, int n_in,
                              void* d_out, int out_size, void* d_ws, size_t ws_size,
                              hipStream_t stream) {
    const float* x    = (const float*)d_in[0];
    // d_in[1] = mask (int32 tril) — causal is hardcoded
    const float* Wqkv = (const float*)d_in[2];
    const float* Wout = (const float*)d_in[3];
    float* out = (float*)d_out;

    char* ws = (char*)d_ws;
    bf16* x_bf    = (bf16*)(ws);                  //  8 MB  [4096,1024]
    bf16* wqkv_bf = (bf16*)(ws + 8388608);        //  6 MB  [3072,1024]
    bf16* wout_bf = (bf16*)(ws + 14680064);       //  2 MB  [1024,1024]
    bf16* q       = (bf16*)(ws + 16777216);       //  8 MB  [32,2048,64] (pre-scaled)
    bf16* k       = (bf16*)(ws + 25165824);       //  8 MB
    bf16* v       = (bf16*)(ws + 33554432);       //  8 MB
    bf16* ao      = (bf16*)(ws + 41943040);       //  8 MB  [4096,1024]

    cast_all<<<8192, 256, 0, stream>>>(x, Wqkv, Wout, x_bf, wqkv_bf, wout_bf);
    gemm128_qkv<<<dim3(32, 24), 256, 0, stream>>>(x_bf, wqkv_bf, q, k, v, 1024);
    flash_attn<<<dim3(32, 16), 256, 0, stream>>>(q, k, v, ao);
    gemm_out<<<dim3(32, 16), 256, 0, stream>>>(ao, wout_bf, out, 1024, 1024);
}